// Round 4
// baseline (726.644 us; speedup 1.0000x reference)
//
#include <hip/hip_runtime.h>

constexpr int N_IN   = 128;
constexpr int N_OUT  = 32;
constexpr int RANGE  = 512;            // output nodes per block
constexpr int STRIDE = N_OUT + 1;      // 33: break LDS bank alignment
constexpr int WIN    = 16384;          // edge window per scan phase
constexpr int BLK    = 512;            // threads per block (8 waves)

// ---------------- Kernel 1: h = feat @ W ----------------
__global__ __launch_bounds__(256) void gemm_h(
    const float* __restrict__ feat, const float* __restrict__ W,
    float* __restrict__ h, int n)
{
    __shared__ float Ws[N_IN * N_OUT];  // 16 KB
    for (int i = threadIdx.x; i < (N_IN * N_OUT) / 4; i += 256)
        reinterpret_cast<float4*>(Ws)[i] = reinterpret_cast<const float4*>(W)[i];
    __syncthreads();

    int gid = blockIdx.x * 256 + threadIdx.x;
    int row = gid >> 3;
    if (row >= n) return;
    int cg = (gid & 7) * 4;

    const float4* frow = reinterpret_cast<const float4*>(feat + (size_t)row * N_IN);
    float4 acc = make_float4(0.f, 0.f, 0.f, 0.f);
    #pragma unroll
    for (int k4 = 0; k4 < N_IN / 4; ++k4) {
        float4 f = frow[k4];
        int k = k4 * 4;
        float4 w0 = *reinterpret_cast<const float4*>(&Ws[(k + 0) * N_OUT + cg]);
        float4 w1 = *reinterpret_cast<const float4*>(&Ws[(k + 1) * N_OUT + cg]);
        float4 w2 = *reinterpret_cast<const float4*>(&Ws[(k + 2) * N_OUT + cg]);
        float4 w3 = *reinterpret_cast<const float4*>(&Ws[(k + 3) * N_OUT + cg]);
        acc.x += f.x * w0.x + f.y * w1.x + f.z * w2.x + f.w * w3.x;
        acc.y += f.x * w0.y + f.y * w1.y + f.z * w2.y + f.w * w3.y;
        acc.z += f.x * w0.z + f.y * w1.z + f.z * w2.z + f.w * w3.z;
        acc.w += f.x * w0.w + f.y * w1.w + f.z * w2.w + f.w * w3.w;
    }
    *reinterpret_cast<float4*>(h + (size_t)row * N_OUT + cg) = acc;
}

// ---------------- Kernel 2: LDS-accumulated graph conv ----------------
// Block b owns nodes [b*RANGE, b*RANGE+RANGE). Full accumulator tile lives
// in LDS (stride 33 randomizes banks vs node index). Stream all edges in
// windows: scan+compact passing edge offsets (u16) into an LDS queue, then
// process densely (8 threads/edge: coalesced 128B h-row read + ds_add_f32).
// Single clean float4 store of the tile at the end. Zero global atomics,
// zero scattered global writes.
__global__ __launch_bounds__(BLK) void graph_conv(
    const float* __restrict__ h, const float* __restrict__ edge_w,
    const int* __restrict__ src, const int* __restrict__ dst,
    float* __restrict__ out, int n, int E)
{
    __shared__ float acc[RANGE * STRIDE];          // 67.6 KB
    __shared__ unsigned short q[WIN];              // 32 KB (cap = window size: overflow-proof)
    __shared__ int qn;

    const int tid = threadIdx.x;
    const int lo  = blockIdx.x * RANGE;
    const int hi  = min(lo + RANGE, n);

    for (int i = tid; i < RANGE * STRIDE; i += BLK) acc[i] = 0.f;
    if (tid == 0) qn = 0;
    __syncthreads();

    const int gid = tid >> 3;
    const int cg  = (tid & 7) * 4;

    for (int wbase = 0; wbase < E; wbase += WIN) {
        const int wend = min(wbase + WIN, E);

        // --- scan & compact ---
        for (int b = wbase + tid * 4; b < wend; b += BLK * 4) {
            if (b + 3 < wend) {
                int4 dv = *reinterpret_cast<const int4*>(dst + b);
                #pragma unroll
                for (int k = 0; k < 4; ++k) {
                    int d = (&dv.x)[k];
                    if (d >= lo && d < hi) {
                        int p = atomicAdd(&qn, 1);
                        q[p] = (unsigned short)(b + k - wbase);
                    }
                }
            } else {
                for (int e = b; e < wend; ++e) {
                    int d = dst[e];
                    if (d >= lo && d < hi) {
                        int p = atomicAdd(&qn, 1);
                        q[p] = (unsigned short)(e - wbase);
                    }
                }
            }
        }
        __syncthreads();

        // --- process queue: 8 threads per edge ---
        const int cnt = qn;
        for (int i = gid; i < cnt; i += BLK / 8) {
            int eid = wbase + (int)q[i];
            int d   = dst[eid];
            int s   = src[eid];
            float w = edge_w[eid];
            float4 hv = *reinterpret_cast<const float4*>(h + (size_t)s * N_OUT + cg);
            float* a = &acc[(d - lo) * STRIDE + cg];
            atomicAdd(a + 0, hv.x * w);
            atomicAdd(a + 1, hv.y * w);
            atomicAdd(a + 2, hv.z * w);
            atomicAdd(a + 3, hv.w * w);
        }
        __syncthreads();
        if (tid == 0) qn = 0;
        __syncthreads();
    }

    // --- clean coalesced store of the tile ---
    for (int i = tid; i < RANGE * 8; i += BLK) {
        int r  = i >> 3;
        int c4 = (i & 7) * 4;
        int node = lo + r;
        if (node < n) {
            float4 v = make_float4(acc[r * STRIDE + c4 + 0],
                                   acc[r * STRIDE + c4 + 1],
                                   acc[r * STRIDE + c4 + 2],
                                   acc[r * STRIDE + c4 + 3]);
            *reinterpret_cast<float4*>(out + (size_t)node * N_OUT + c4) = v;
        }
    }
}

// ---------------- Fallback: fused (no workspace) ----------------
__global__ __launch_bounds__(256) void fused_edge(
    const float* __restrict__ feat, const float* __restrict__ W,
    const float* __restrict__ edge_w, const int* __restrict__ src,
    const int* __restrict__ dst, float* __restrict__ out, int E)
{
    __shared__ float Ws[N_IN * N_OUT];
    for (int i = threadIdx.x; i < (N_IN * N_OUT) / 4; i += 256)
        reinterpret_cast<float4*>(Ws)[i] = reinterpret_cast<const float4*>(W)[i];
    __syncthreads();
    int gid = blockIdx.x * 256 + threadIdx.x;
    int e = gid >> 3;
    if (e >= E) return;
    int cg = (gid & 7) * 4;
    int s = src[e];
    int d = dst[e];
    float w = edge_w[e];
    const float4* frow = reinterpret_cast<const float4*>(feat + (size_t)s * N_IN);
    float4 acc = make_float4(0.f, 0.f, 0.f, 0.f);
    #pragma unroll
    for (int k4 = 0; k4 < N_IN / 4; ++k4) {
        float4 f = frow[k4];
        int k = k4 * 4;
        float4 w0 = *reinterpret_cast<const float4*>(&Ws[(k + 0) * N_OUT + cg]);
        float4 w1 = *reinterpret_cast<const float4*>(&Ws[(k + 1) * N_OUT + cg]);
        float4 w2 = *reinterpret_cast<const float4*>(&Ws[(k + 2) * N_OUT + cg]);
        float4 w3 = *reinterpret_cast<const float4*>(&Ws[(k + 3) * N_OUT + cg]);
        acc.x += f.x * w0.x + f.y * w1.x + f.z * w2.x + f.w * w3.x;
        acc.y += f.x * w0.y + f.y * w1.y + f.z * w2.y + f.w * w3.y;
        acc.z += f.x * w0.z + f.y * w1.z + f.z * w2.z + f.w * w3.z;
        acc.w += f.x * w0.w + f.y * w1.w + f.z * w2.w + f.w * w3.w;
    }
    float* o = out + (size_t)d * N_OUT + cg;
    atomicAdd(o + 0, acc.x * w);
    atomicAdd(o + 1, acc.y * w);
    atomicAdd(o + 2, acc.z * w);
    atomicAdd(o + 3, acc.w * w);
}

extern "C" void kernel_launch(void* const* d_in, const int* in_sizes, int n_in,
                              void* d_out, int out_size, void* d_ws, size_t ws_size,
                              hipStream_t stream) {
    const float* feat   = (const float*)d_in[0];
    const float* W      = (const float*)d_in[1];
    const float* edge_w = (const float*)d_in[2];
    const int*   src    = (const int*)d_in[3];
    const int*   dst    = (const int*)d_in[4];
    float* out = (float*)d_out;

    int n = in_sizes[0] / N_IN;   // 100000
    int E = in_sizes[2];          // 1600000

    size_t h_bytes = (size_t)n * N_OUT * sizeof(float);
    if (ws_size >= h_bytes) {
        float* h = (float*)d_ws;
        long gthreads = (long)n * 8;
        gemm_h<<<(int)((gthreads + 255) / 256), 256, 0, stream>>>(feat, W, h, n);

        int nranges = (n + RANGE - 1) / RANGE;   // 196
        graph_conv<<<nranges, BLK, 0, stream>>>(h, edge_w, src, dst, out, n, E);
    } else {
        hipMemsetAsync(d_out, 0, (size_t)out_size * sizeof(float), stream);
        long sthreads = (long)E * 8;
        fused_edge<<<(int)((sthreads + 255) / 256), 256, 0, stream>>>(feat, W, edge_w, src, dst, out, E);
    }
}

// Round 5
// 400.536 us; speedup vs baseline: 1.8142x; 1.8142x over previous
//
#include <hip/hip_runtime.h>

constexpr int N_IN     = 128;
constexpr int N_OUT    = 32;
constexpr int RANGE    = 256;     // nodes per bucket (bucket = dst >> 8)
constexpr int C_CHUNKS = 256;     // edge chunks
constexpr int SCAN_B   = 512;
constexpr int MAXNB    = 512;     // max buckets supported by LDS cursor arrays
constexpr int ACC_STR  = N_OUT + 1;  // 33

// ---------------- Kernel 1: h = feat @ W ----------------
__global__ __launch_bounds__(256) void gemm_h(
    const float* __restrict__ feat, const float* __restrict__ W,
    float* __restrict__ h, int n)
{
    __shared__ float Ws[N_IN * N_OUT];  // 16 KB
    for (int i = threadIdx.x; i < (N_IN * N_OUT) / 4; i += 256)
        reinterpret_cast<float4*>(Ws)[i] = reinterpret_cast<const float4*>(W)[i];
    __syncthreads();

    int gid = blockIdx.x * 256 + threadIdx.x;
    int row = gid >> 3;
    if (row >= n) return;
    int cg = (gid & 7) * 4;

    const float4* frow = reinterpret_cast<const float4*>(feat + (size_t)row * N_IN);
    float4 acc = make_float4(0.f, 0.f, 0.f, 0.f);
    #pragma unroll
    for (int k4 = 0; k4 < N_IN / 4; ++k4) {
        float4 f = frow[k4];
        int k = k4 * 4;
        float4 w0 = *reinterpret_cast<const float4*>(&Ws[(k + 0) * N_OUT + cg]);
        float4 w1 = *reinterpret_cast<const float4*>(&Ws[(k + 1) * N_OUT + cg]);
        float4 w2 = *reinterpret_cast<const float4*>(&Ws[(k + 2) * N_OUT + cg]);
        float4 w3 = *reinterpret_cast<const float4*>(&Ws[(k + 3) * N_OUT + cg]);
        acc.x += f.x * w0.x + f.y * w1.x + f.z * w2.x + f.w * w3.x;
        acc.y += f.x * w0.y + f.y * w1.y + f.z * w2.y + f.w * w3.y;
        acc.z += f.x * w0.z + f.y * w1.z + f.z * w2.z + f.w * w3.z;
        acc.w += f.x * w0.w + f.y * w1.w + f.z * w2.w + f.w * w3.w;
    }
    *reinterpret_cast<float4*>(h + (size_t)row * N_OUT + cg) = acc;
}

// ---------------- count: per-chunk bucket histogram (LDS atomics only) ----
__global__ __launch_bounds__(256) void count_k(
    const int* __restrict__ dst, int* __restrict__ cnt, int E, int NB, int epc)
{
    __shared__ int hist[MAXNB];
    int c = blockIdx.x;
    for (int i = threadIdx.x; i < NB; i += 256) hist[i] = 0;
    __syncthreads();
    int e0 = c * epc, e1 = min(e0 + epc, E);
    for (int e = e0 + (int)threadIdx.x; e < e1; e += 256)
        atomicAdd(&hist[dst[e] >> 8], 1);
    __syncthreads();
    for (int b = threadIdx.x; b < NB; b += 256)
        cnt[b * C_CHUNKS + c] = hist[b];   // bucket-major matrix
}

// ---------------- hierarchical exclusive scan over m elements -------------
__global__ __launch_bounds__(SCAN_B) void scan1(
    const int* __restrict__ cnt, int* __restrict__ bsum, int m)
{
    __shared__ int s[SCAN_B];
    int g = blockIdx.x * SCAN_B + threadIdx.x;
    s[threadIdx.x] = (g < m) ? cnt[g] : 0;
    __syncthreads();
    for (int off = SCAN_B / 2; off > 0; off >>= 1) {
        if ((int)threadIdx.x < off) s[threadIdx.x] += s[threadIdx.x + off];
        __syncthreads();
    }
    if (threadIdx.x == 0) bsum[blockIdx.x] = s[0];
}

__global__ __launch_bounds__(SCAN_B) void scan2(int* __restrict__ bsum, int nb)
{
    __shared__ int s[SCAN_B];
    int t = threadIdx.x;
    int v = (t < nb) ? bsum[t] : 0;
    s[t] = v;
    __syncthreads();
    for (int off = 1; off < SCAN_B; off <<= 1) {
        int x = (t >= off) ? s[t - off] : 0;
        __syncthreads();
        s[t] += x;
        __syncthreads();
    }
    if (t < nb) bsum[t] = s[t] - v;  // exclusive
}

// in-place: base[g] = exclusive_scan(cnt)[g]  (base may alias cnt)
__global__ __launch_bounds__(SCAN_B) void scan3(
    int* __restrict__ base, const int* __restrict__ bsum, int m)
{
    __shared__ int s[SCAN_B];
    int t = threadIdx.x;
    int g = blockIdx.x * SCAN_B + t;
    int v = (g < m) ? base[g] : 0;
    s[t] = v;
    __syncthreads();
    for (int off = 1; off < SCAN_B; off <<= 1) {
        int x = (t >= off) ? s[t - off] : 0;
        __syncthreads();
        s[t] += x;
        __syncthreads();
    }
    if (g < m) base[g] = s[t] - v + bsum[blockIdx.x];
}

// ---------------- partition: bin (src|loc, w) pairs by bucket --------------
// Rank within (chunk,bucket) via LDS cursors seeded from the scanned matrix:
// zero global atomics; per-bucket output positions are sequential, so L2
// assembles full lines (low write amplification).
__global__ __launch_bounds__(256) void partition_k(
    const int* __restrict__ src, const int* __restrict__ dst,
    const float* __restrict__ w, const int* __restrict__ base,
    int2* __restrict__ sw, int E, int NB, int epc)
{
    __shared__ int cur[MAXNB];
    int c = blockIdx.x;
    for (int b = threadIdx.x; b < NB; b += 256)
        cur[b] = base[b * C_CHUNKS + c];
    __syncthreads();
    int e0 = c * epc, e1 = min(e0 + epc, E);
    for (int e = e0 + (int)threadIdx.x; e < e1; e += 256) {
        int d = dst[e];
        int b = d >> 8;
        int loc = d & (RANGE - 1);
        int pos = atomicAdd(&cur[b], 1);
        sw[pos] = make_int2(src[e] | (loc << 17), __float_as_int(w[e]));
    }
}

// ---------------- conv: per-bucket LDS tile accumulate, clean stores -------
__global__ __launch_bounds__(512) void conv_k(
    const float* __restrict__ h, const int2* __restrict__ sw,
    const int* __restrict__ base, float* __restrict__ out,
    int n, int E, int NB)
{
    __shared__ float acc[RANGE * ACC_STR];   // 33.8 KB
    int b   = blockIdx.x;
    int tid = threadIdx.x;
    for (int i = tid; i < RANGE * ACC_STR; i += 512) acc[i] = 0.f;
    __syncthreads();

    int seg0 = base[b * C_CHUNKS];
    int seg1 = (b + 1 < NB) ? base[(b + 1) * C_CHUNKS] : E;

    int g  = tid >> 3;
    int cg = (tid & 7) * 4;
    for (int j = seg0 + g; j < seg1; j += 64) {
        int2 p = sw[j];
        int s   = p.x & 0x1FFFF;
        int loc = p.x >> 17;
        float wv = __int_as_float(p.y);
        float4 hv = *reinterpret_cast<const float4*>(h + (size_t)s * N_OUT + cg);
        float* a = &acc[loc * ACC_STR + cg];
        atomicAdd(a + 0, hv.x * wv);
        atomicAdd(a + 1, hv.y * wv);
        atomicAdd(a + 2, hv.z * wv);
        atomicAdd(a + 3, hv.w * wv);
    }
    __syncthreads();

    int lo = b * RANGE;
    for (int i = tid; i < RANGE * 8; i += 512) {
        int r  = i >> 3;
        int c4 = (i & 7) * 4;
        int node = lo + r;
        if (node < n) {
            float4 v = make_float4(acc[r * ACC_STR + c4 + 0],
                                   acc[r * ACC_STR + c4 + 1],
                                   acc[r * ACC_STR + c4 + 2],
                                   acc[r * ACC_STR + c4 + 3]);
            *reinterpret_cast<float4*>(out + (size_t)node * N_OUT + c4) = v;
        }
    }
}

// ---------------- Fallback: fused (no workspace) ----------------
__global__ __launch_bounds__(256) void fused_edge(
    const float* __restrict__ feat, const float* __restrict__ W,
    const float* __restrict__ edge_w, const int* __restrict__ src,
    const int* __restrict__ dst, float* __restrict__ out, int E)
{
    __shared__ float Ws[N_IN * N_OUT];
    for (int i = threadIdx.x; i < (N_IN * N_OUT) / 4; i += 256)
        reinterpret_cast<float4*>(Ws)[i] = reinterpret_cast<const float4*>(W)[i];
    __syncthreads();
    int gid = blockIdx.x * 256 + threadIdx.x;
    int e = gid >> 3;
    if (e >= E) return;
    int cg = (gid & 7) * 4;
    int s = src[e];
    int d = dst[e];
    float w = edge_w[e];
    const float4* frow = reinterpret_cast<const float4*>(feat + (size_t)s * N_IN);
    float4 acc = make_float4(0.f, 0.f, 0.f, 0.f);
    #pragma unroll
    for (int k4 = 0; k4 < N_IN / 4; ++k4) {
        float4 f = frow[k4];
        int k = k4 * 4;
        float4 w0 = *reinterpret_cast<const float4*>(&Ws[(k + 0) * N_OUT + cg]);
        float4 w1 = *reinterpret_cast<const float4*>(&Ws[(k + 1) * N_OUT + cg]);
        float4 w2 = *reinterpret_cast<const float4*>(&Ws[(k + 2) * N_OUT + cg]);
        float4 w3 = *reinterpret_cast<const float4*>(&Ws[(k + 3) * N_OUT + cg]);
        acc.x += f.x * w0.x + f.y * w1.x + f.z * w2.x + f.w * w3.x;
        acc.y += f.x * w0.y + f.y * w1.y + f.z * w2.y + f.w * w3.y;
        acc.z += f.x * w0.z + f.y * w1.z + f.z * w2.z + f.w * w3.z;
        acc.w += f.x * w0.w + f.y * w1.w + f.z * w2.w + f.w * w3.w;
    }
    float* o = out + (size_t)d * N_OUT + cg;
    atomicAdd(o + 0, acc.x * w);
    atomicAdd(o + 1, acc.y * w);
    atomicAdd(o + 2, acc.z * w);
    atomicAdd(o + 3, acc.w * w);
}

extern "C" void kernel_launch(void* const* d_in, const int* in_sizes, int n_in,
                              void* d_out, int out_size, void* d_ws, size_t ws_size,
                              hipStream_t stream) {
    const float* feat   = (const float*)d_in[0];
    const float* W      = (const float*)d_in[1];
    const float* edge_w = (const float*)d_in[2];
    const int*   src    = (const int*)d_in[3];
    const int*   dst    = (const int*)d_in[4];
    float* out = (float*)d_out;

    int n = in_sizes[0] / N_IN;   // 100000
    int E = in_sizes[2];          // 1600000

    int NB  = (n + RANGE - 1) / RANGE;       // 391 for n=100000
    int m   = NB * C_CHUNKS;                 // count-matrix elements
    int nsb = (m + SCAN_B - 1) / SCAN_B;     // scan blocks (196)
    int epc = (E + C_CHUNKS - 1) / C_CHUNKS; // edges per chunk (6250)

    // workspace layout
    size_t off_h    = 0;
    size_t off_base = off_h + (size_t)n * N_OUT * sizeof(float);
    size_t off_bsum = off_base + (size_t)m * sizeof(int);
    size_t off_sw   = (off_bsum + (size_t)SCAN_B * sizeof(int) + 15) & ~(size_t)15;
    size_t need     = off_sw + (size_t)E * sizeof(int2);

    char* ws = (char*)d_ws;

    bool ok = (ws_size >= need) && (n <= (1 << 17)) && (NB <= MAXNB) &&
              (nsb <= SCAN_B);

    if (ok) {
        float* h    = (float*)(ws + off_h);
        int*   base = (int*)(ws + off_base);   // cnt, scanned in place
        int*   bsum = (int*)(ws + off_bsum);
        int2*  sw   = (int2*)(ws + off_sw);

        long gthreads = (long)n * 8;
        gemm_h<<<(int)((gthreads + 255) / 256), 256, 0, stream>>>(feat, W, h, n);

        count_k<<<C_CHUNKS, 256, 0, stream>>>(dst, base, E, NB, epc);
        scan1<<<nsb, SCAN_B, 0, stream>>>(base, bsum, m);
        scan2<<<1, SCAN_B, 0, stream>>>(bsum, nsb);
        scan3<<<nsb, SCAN_B, 0, stream>>>(base, bsum, m);
        partition_k<<<C_CHUNKS, 256, 0, stream>>>(src, dst, edge_w, base, sw, E, NB, epc);
        conv_k<<<NB, 512, 0, stream>>>(h, sw, base, out, n, E, NB);
    } else {
        hipMemsetAsync(d_out, 0, (size_t)out_size * sizeof(float), stream);
        long sthreads = (long)E * 8;
        fused_edge<<<(int)((sthreads + 255) / 256), 256, 0, stream>>>(feat, W, edge_w, src, dst, out, E);
    }
}

// Round 6
// 379.246 us; speedup vs baseline: 1.9160x; 1.0561x over previous
//
#include <hip/hip_runtime.h>

constexpr int N_IN     = 128;
constexpr int N_OUT    = 32;
constexpr int LOG_R    = 6;
constexpr int RANGE    = 1 << LOG_R;  // 64 nodes per bucket
constexpr int C_CHUNKS = 128;         // edge chunks
constexpr int SCAN_B   = 512;
constexpr int MAXNB    = 2048;        // max buckets (LDS cursor arrays)
constexpr int ACC_STR  = N_OUT + 1;   // 33

// ---------------- Kernel 1: h = feat @ W ----------------
__global__ __launch_bounds__(256) void gemm_h(
    const float* __restrict__ feat, const float* __restrict__ W,
    float* __restrict__ h, int n)
{
    __shared__ float Ws[N_IN * N_OUT];  // 16 KB
    for (int i = threadIdx.x; i < (N_IN * N_OUT) / 4; i += 256)
        reinterpret_cast<float4*>(Ws)[i] = reinterpret_cast<const float4*>(W)[i];
    __syncthreads();

    int gid = blockIdx.x * 256 + threadIdx.x;
    int row = gid >> 3;
    if (row >= n) return;
    int cg = (gid & 7) * 4;

    const float4* frow = reinterpret_cast<const float4*>(feat + (size_t)row * N_IN);
    float4 acc = make_float4(0.f, 0.f, 0.f, 0.f);
    #pragma unroll
    for (int k4 = 0; k4 < N_IN / 4; ++k4) {
        float4 f = frow[k4];
        int k = k4 * 4;
        float4 w0 = *reinterpret_cast<const float4*>(&Ws[(k + 0) * N_OUT + cg]);
        float4 w1 = *reinterpret_cast<const float4*>(&Ws[(k + 1) * N_OUT + cg]);
        float4 w2 = *reinterpret_cast<const float4*>(&Ws[(k + 2) * N_OUT + cg]);
        float4 w3 = *reinterpret_cast<const float4*>(&Ws[(k + 3) * N_OUT + cg]);
        acc.x += f.x * w0.x + f.y * w1.x + f.z * w2.x + f.w * w3.x;
        acc.y += f.x * w0.y + f.y * w1.y + f.z * w2.y + f.w * w3.y;
        acc.z += f.x * w0.z + f.y * w1.z + f.z * w2.z + f.w * w3.z;
        acc.w += f.x * w0.w + f.y * w1.w + f.z * w2.w + f.w * w3.w;
    }
    *reinterpret_cast<float4*>(h + (size_t)row * N_OUT + cg) = acc;
}

// ---------------- count: per-chunk bucket histogram (LDS atomics only) ----
__global__ __launch_bounds__(256) void count_k(
    const int* __restrict__ dst, int* __restrict__ cnt, int E, int NB, int epc)
{
    __shared__ int hist[MAXNB];
    int c = blockIdx.x;
    for (int i = threadIdx.x; i < NB; i += 256) hist[i] = 0;
    __syncthreads();
    int e0 = c * epc, e1 = min(e0 + epc, E);
    for (int e = e0 + (int)threadIdx.x; e < e1; e += 256)
        atomicAdd(&hist[dst[e] >> LOG_R], 1);
    __syncthreads();
    for (int b = threadIdx.x; b < NB; b += 256)
        cnt[b * C_CHUNKS + c] = hist[b];   // bucket-major matrix
}

// ---------------- hierarchical exclusive scan over m elements -------------
__global__ __launch_bounds__(SCAN_B) void scan1(
    const int* __restrict__ cnt, int* __restrict__ bsum, int m)
{
    __shared__ int s[SCAN_B];
    int g = blockIdx.x * SCAN_B + threadIdx.x;
    s[threadIdx.x] = (g < m) ? cnt[g] : 0;
    __syncthreads();
    for (int off = SCAN_B / 2; off > 0; off >>= 1) {
        if ((int)threadIdx.x < off) s[threadIdx.x] += s[threadIdx.x + off];
        __syncthreads();
    }
    if (threadIdx.x == 0) bsum[blockIdx.x] = s[0];
}

__global__ __launch_bounds__(SCAN_B) void scan2(int* __restrict__ bsum, int nb)
{
    __shared__ int s[SCAN_B];
    int t = threadIdx.x;
    int v = (t < nb) ? bsum[t] : 0;
    s[t] = v;
    __syncthreads();
    for (int off = 1; off < SCAN_B; off <<= 1) {
        int x = (t >= off) ? s[t - off] : 0;
        __syncthreads();
        s[t] += x;
        __syncthreads();
    }
    if (t < nb) bsum[t] = s[t] - v;  // exclusive
}

// in-place: base[g] = exclusive_scan(cnt)[g]  (base may alias cnt)
__global__ __launch_bounds__(SCAN_B) void scan3(
    int* __restrict__ base, const int* __restrict__ bsum, int m)
{
    __shared__ int s[SCAN_B];
    int t = threadIdx.x;
    int g = blockIdx.x * SCAN_B + t;
    int v = (g < m) ? base[g] : 0;
    s[t] = v;
    __syncthreads();
    for (int off = 1; off < SCAN_B; off <<= 1) {
        int x = (t >= off) ? s[t - off] : 0;
        __syncthreads();
        s[t] += x;
        __syncthreads();
    }
    if (g < m) base[g] = s[t] - v + bsum[blockIdx.x];
}

// ---------------- partition: bin (src|loc, w) pairs by bucket --------------
__global__ __launch_bounds__(256) void partition_k(
    const int* __restrict__ src, const int* __restrict__ dst,
    const float* __restrict__ w, const int* __restrict__ base,
    int2* __restrict__ sw, int E, int NB, int epc)
{
    __shared__ int cur[MAXNB];
    int c = blockIdx.x;
    for (int b = threadIdx.x; b < NB; b += 256)
        cur[b] = base[b * C_CHUNKS + c];
    __syncthreads();
    int e0 = c * epc, e1 = min(e0 + epc, E);
    for (int e = e0 + (int)threadIdx.x; e < e1; e += 256) {
        int d = dst[e];
        int b = d >> LOG_R;
        int loc = d & (RANGE - 1);
        int pos = atomicAdd(&cur[b], 1);
        sw[pos] = make_int2(src[e] | (loc << 17), __float_as_int(w[e]));
    }
}

// ---------------- conv: per-bucket LDS tile accumulate, clean stores -------
// 1563 blocks x 256 threads; 32 groups of 8 threads; 4-edge unrolled inner
// loop gives 4 independent h-row gathers in flight per lane (MLP).
__global__ __launch_bounds__(256) void conv_k(
    const float* __restrict__ h, const int2* __restrict__ sw,
    const int* __restrict__ base, float* __restrict__ out,
    int n, int E, int NB)
{
    __shared__ float acc[RANGE * ACC_STR];   // 8.4 KB
    int b   = blockIdx.x;
    int tid = threadIdx.x;
    for (int i = tid; i < RANGE * ACC_STR; i += 256) acc[i] = 0.f;
    __syncthreads();

    int seg0 = base[b * C_CHUNKS];
    int seg1 = (b + 1 < NB) ? base[(b + 1) * C_CHUNKS] : E;

    int g  = tid >> 3;          // 0..31
    int cg = (tid & 7) * 4;

    int j = seg0 + g;
    // 4-wide unroll: independent loads fill the memory pipeline
    for (; j + 96 < seg1; j += 128) {
        int2 p0 = sw[j];
        int2 p1 = sw[j + 32];
        int2 p2 = sw[j + 64];
        int2 p3 = sw[j + 96];
        float4 h0 = *reinterpret_cast<const float4*>(h + (size_t)(p0.x & 0x1FFFF) * N_OUT + cg);
        float4 h1 = *reinterpret_cast<const float4*>(h + (size_t)(p1.x & 0x1FFFF) * N_OUT + cg);
        float4 h2 = *reinterpret_cast<const float4*>(h + (size_t)(p2.x & 0x1FFFF) * N_OUT + cg);
        float4 h3 = *reinterpret_cast<const float4*>(h + (size_t)(p3.x & 0x1FFFF) * N_OUT + cg);
        float w0 = __int_as_float(p0.y), w1 = __int_as_float(p1.y);
        float w2 = __int_as_float(p2.y), w3 = __int_as_float(p3.y);
        float* a0 = &acc[(p0.x >> 17) * ACC_STR + cg];
        float* a1 = &acc[(p1.x >> 17) * ACC_STR + cg];
        float* a2 = &acc[(p2.x >> 17) * ACC_STR + cg];
        float* a3 = &acc[(p3.x >> 17) * ACC_STR + cg];
        atomicAdd(a0 + 0, h0.x * w0); atomicAdd(a0 + 1, h0.y * w0);
        atomicAdd(a0 + 2, h0.z * w0); atomicAdd(a0 + 3, h0.w * w0);
        atomicAdd(a1 + 0, h1.x * w1); atomicAdd(a1 + 1, h1.y * w1);
        atomicAdd(a1 + 2, h1.z * w1); atomicAdd(a1 + 3, h1.w * w1);
        atomicAdd(a2 + 0, h2.x * w2); atomicAdd(a2 + 1, h2.y * w2);
        atomicAdd(a2 + 2, h2.z * w2); atomicAdd(a2 + 3, h2.w * w2);
        atomicAdd(a3 + 0, h3.x * w3); atomicAdd(a3 + 1, h3.y * w3);
        atomicAdd(a3 + 2, h3.z * w3); atomicAdd(a3 + 3, h3.w * w3);
    }
    for (; j < seg1; j += 32) {
        int2 p = sw[j];
        int s   = p.x & 0x1FFFF;
        int loc = p.x >> 17;
        float wv = __int_as_float(p.y);
        float4 hv = *reinterpret_cast<const float4*>(h + (size_t)s * N_OUT + cg);
        float* a = &acc[loc * ACC_STR + cg];
        atomicAdd(a + 0, hv.x * wv);
        atomicAdd(a + 1, hv.y * wv);
        atomicAdd(a + 2, hv.z * wv);
        atomicAdd(a + 3, hv.w * wv);
    }
    __syncthreads();

    int lo = b * RANGE;
    for (int i = tid; i < RANGE * 8; i += 256) {
        int r  = i >> 3;
        int c4 = (i & 7) * 4;
        int node = lo + r;
        if (node < n) {
            float4 v = make_float4(acc[r * ACC_STR + c4 + 0],
                                   acc[r * ACC_STR + c4 + 1],
                                   acc[r * ACC_STR + c4 + 2],
                                   acc[r * ACC_STR + c4 + 3]);
            *reinterpret_cast<float4*>(out + (size_t)node * N_OUT + c4) = v;
        }
    }
}

// ---------------- Fallback: fused (no workspace) ----------------
__global__ __launch_bounds__(256) void fused_edge(
    const float* __restrict__ feat, const float* __restrict__ W,
    const float* __restrict__ edge_w, const int* __restrict__ src,
    const int* __restrict__ dst, float* __restrict__ out, int E)
{
    __shared__ float Ws[N_IN * N_OUT];
    for (int i = threadIdx.x; i < (N_IN * N_OUT) / 4; i += 256)
        reinterpret_cast<float4*>(Ws)[i] = reinterpret_cast<const float4*>(W)[i];
    __syncthreads();
    int gid = blockIdx.x * 256 + threadIdx.x;
    int e = gid >> 3;
    if (e >= E) return;
    int cg = (gid & 7) * 4;
    int s = src[e];
    int d = dst[e];
    float w = edge_w[e];
    const float4* frow = reinterpret_cast<const float4*>(feat + (size_t)s * N_IN);
    float4 acc = make_float4(0.f, 0.f, 0.f, 0.f);
    #pragma unroll
    for (int k4 = 0; k4 < N_IN / 4; ++k4) {
        float4 f = frow[k4];
        int k = k4 * 4;
        float4 w0 = *reinterpret_cast<const float4*>(&Ws[(k + 0) * N_OUT + cg]);
        float4 w1 = *reinterpret_cast<const float4*>(&Ws[(k + 1) * N_OUT + cg]);
        float4 w2 = *reinterpret_cast<const float4*>(&Ws[(k + 2) * N_OUT + cg]);
        float4 w3 = *reinterpret_cast<const float4*>(&Ws[(k + 3) * N_OUT + cg]);
        acc.x += f.x * w0.x + f.y * w1.x + f.z * w2.x + f.w * w3.x;
        acc.y += f.x * w0.y + f.y * w1.y + f.z * w2.y + f.w * w3.y;
        acc.z += f.x * w0.z + f.y * w1.z + f.z * w2.z + f.w * w3.z;
        acc.w += f.x * w0.w + f.y * w1.w + f.z * w2.w + f.w * w3.w;
    }
    float* o = out + (size_t)d * N_OUT + cg;
    atomicAdd(o + 0, acc.x * w);
    atomicAdd(o + 1, acc.y * w);
    atomicAdd(o + 2, acc.z * w);
    atomicAdd(o + 3, acc.w * w);
}

extern "C" void kernel_launch(void* const* d_in, const int* in_sizes, int n_in,
                              void* d_out, int out_size, void* d_ws, size_t ws_size,
                              hipStream_t stream) {
    const float* feat   = (const float*)d_in[0];
    const float* W      = (const float*)d_in[1];
    const float* edge_w = (const float*)d_in[2];
    const int*   src    = (const int*)d_in[3];
    const int*   dst    = (const int*)d_in[4];
    float* out = (float*)d_out;

    int n = in_sizes[0] / N_IN;   // 100000
    int E = in_sizes[2];          // 1600000

    int NB  = (n + RANGE - 1) / RANGE;       // 1563
    int m   = NB * C_CHUNKS;                 // 200,064
    int nsb = (m + SCAN_B - 1) / SCAN_B;     // 391
    int epc = (E + C_CHUNKS - 1) / C_CHUNKS; // 12500

    size_t off_h    = 0;
    size_t off_base = off_h + (size_t)n * N_OUT * sizeof(float);
    size_t off_bsum = off_base + (size_t)m * sizeof(int);
    size_t off_sw   = (off_bsum + (size_t)SCAN_B * sizeof(int) + 15) & ~(size_t)15;
    size_t need     = off_sw + (size_t)E * sizeof(int2);

    char* ws = (char*)d_ws;

    bool ok = (ws_size >= need) && (n <= (1 << 17)) && (NB <= MAXNB) &&
              (nsb <= SCAN_B);

    if (ok) {
        float* h    = (float*)(ws + off_h);
        int*   base = (int*)(ws + off_base);   // cnt, scanned in place
        int*   bsum = (int*)(ws + off_bsum);
        int2*  sw   = (int2*)(ws + off_sw);

        long gthreads = (long)n * 8;
        gemm_h<<<(int)((gthreads + 255) / 256), 256, 0, stream>>>(feat, W, h, n);

        count_k<<<C_CHUNKS, 256, 0, stream>>>(dst, base, E, NB, epc);
        scan1<<<nsb, SCAN_B, 0, stream>>>(base, bsum, m);
        scan2<<<1, SCAN_B, 0, stream>>>(bsum, nsb);
        scan3<<<nsb, SCAN_B, 0, stream>>>(base, bsum, m);
        partition_k<<<C_CHUNKS, 256, 0, stream>>>(src, dst, edge_w, base, sw, E, NB, epc);
        conv_k<<<NB, 256, 0, stream>>>(h, sw, base, out, n, E, NB);
    } else {
        hipMemsetAsync(d_out, 0, (size_t)out_size * sizeof(float), stream);
        long sthreads = (long)E * 8;
        fused_edge<<<(int)((sthreads + 255) / 256), 256, 0, stream>>>(feat, W, edge_w, src, dst, out, E);
    }
}

// Round 7
// 97.356 us; speedup vs baseline: 7.4638x; 3.8955x over previous
//
#include <hip/hip_runtime.h>

constexpr int N_IN     = 128;
constexpr int N_OUT    = 32;
constexpr int LOG_R    = 6;
constexpr int RANGE    = 1 << LOG_R;  // 64 nodes per bucket
constexpr int C_CHUNKS = 128;         // edge chunks (keeps ws need == R6's, which fit)
constexpr int SCAN_B   = 512;
constexpr int MAXNB    = 2048;        // max buckets (LDS cursor arrays)
constexpr int CHUNK_P  = 2048;        // staged pairs per conv2 pass

// ---------------- Kernel 1: h = feat @ W ----------------
__global__ __launch_bounds__(256) void gemm_h(
    const float* __restrict__ feat, const float* __restrict__ W,
    float* __restrict__ h, int n)
{
    __shared__ float Ws[N_IN * N_OUT];  // 16 KB
    for (int i = threadIdx.x; i < (N_IN * N_OUT) / 4; i += 256)
        reinterpret_cast<float4*>(Ws)[i] = reinterpret_cast<const float4*>(W)[i];
    __syncthreads();

    int gid = blockIdx.x * 256 + threadIdx.x;
    int row = gid >> 3;
    if (row >= n) return;
    int cg = (gid & 7) * 4;

    const float4* frow = reinterpret_cast<const float4*>(feat + (size_t)row * N_IN);
    float4 acc = make_float4(0.f, 0.f, 0.f, 0.f);
    #pragma unroll
    for (int k4 = 0; k4 < N_IN / 4; ++k4) {
        float4 f = frow[k4];
        int k = k4 * 4;
        float4 w0 = *reinterpret_cast<const float4*>(&Ws[(k + 0) * N_OUT + cg]);
        float4 w1 = *reinterpret_cast<const float4*>(&Ws[(k + 1) * N_OUT + cg]);
        float4 w2 = *reinterpret_cast<const float4*>(&Ws[(k + 2) * N_OUT + cg]);
        float4 w3 = *reinterpret_cast<const float4*>(&Ws[(k + 3) * N_OUT + cg]);
        acc.x += f.x * w0.x + f.y * w1.x + f.z * w2.x + f.w * w3.x;
        acc.y += f.x * w0.y + f.y * w1.y + f.z * w2.y + f.w * w3.y;
        acc.z += f.x * w0.z + f.y * w1.z + f.z * w2.z + f.w * w3.z;
        acc.w += f.x * w0.w + f.y * w1.w + f.z * w2.w + f.w * w3.w;
    }
    *reinterpret_cast<float4*>(h + (size_t)row * N_OUT + cg) = acc;
}

// ---------------- count: per-chunk bucket histogram (LDS atomics only) ----
__global__ __launch_bounds__(512) void count_k(
    const int* __restrict__ dst, int* __restrict__ cnt, int E, int NB, int epc)
{
    __shared__ int hist[MAXNB];
    int c = blockIdx.x;
    for (int i = threadIdx.x; i < NB; i += 512) hist[i] = 0;
    __syncthreads();
    int e0 = c * epc, e1 = min(e0 + epc, E);
    for (int e = e0 + (int)threadIdx.x; e < e1; e += 512)
        atomicAdd(&hist[dst[e] >> LOG_R], 1);
    __syncthreads();
    for (int b = threadIdx.x; b < NB; b += 512)
        cnt[b * C_CHUNKS + c] = hist[b];   // bucket-major matrix
}

// ---------------- hierarchical exclusive scan over m elements -------------
__global__ __launch_bounds__(SCAN_B) void scan1(
    const int* __restrict__ cnt, int* __restrict__ bsum, int m)
{
    __shared__ int s[SCAN_B];
    int g = blockIdx.x * SCAN_B + threadIdx.x;
    s[threadIdx.x] = (g < m) ? cnt[g] : 0;
    __syncthreads();
    for (int off = SCAN_B / 2; off > 0; off >>= 1) {
        if ((int)threadIdx.x < off) s[threadIdx.x] += s[threadIdx.x + off];
        __syncthreads();
    }
    if (threadIdx.x == 0) bsum[blockIdx.x] = s[0];
}

// exclusive scan of nb block sums; single block, loops tiles (nb any size)
__global__ __launch_bounds__(SCAN_B) void scan2(int* __restrict__ bsum, int nb)
{
    __shared__ int s[SCAN_B];
    __shared__ int carry;
    int t = threadIdx.x;
    if (t == 0) carry = 0;
    __syncthreads();
    for (int base = 0; base < nb; base += SCAN_B) {
        int g = base + t;
        int v = (g < nb) ? bsum[g] : 0;
        s[t] = v;
        __syncthreads();
        for (int off = 1; off < SCAN_B; off <<= 1) {
            int x = (t >= off) ? s[t - off] : 0;
            __syncthreads();
            s[t] += x;
            __syncthreads();
        }
        if (g < nb) bsum[g] = s[t] - v + carry;
        __syncthreads();
        if (t == 0) carry += s[SCAN_B - 1];
        __syncthreads();
    }
}

// in-place: base[g] = exclusive_scan(cnt)[g] + bsum[block]
__global__ __launch_bounds__(SCAN_B) void scan3(
    int* __restrict__ base, const int* __restrict__ bsum, int m)
{
    __shared__ int s[SCAN_B];
    int t = threadIdx.x;
    int g = blockIdx.x * SCAN_B + t;
    int v = (g < m) ? base[g] : 0;
    s[t] = v;
    __syncthreads();
    for (int off = 1; off < SCAN_B; off <<= 1) {
        int x = (t >= off) ? s[t - off] : 0;
        __syncthreads();
        s[t] += x;
        __syncthreads();
    }
    if (g < m) base[g] = s[t] - v + bsum[blockIdx.x];
}

// ---------------- partition: bin (src|loc, w) pairs by bucket --------------
__global__ __launch_bounds__(512) void partition_k(
    const int* __restrict__ src, const int* __restrict__ dst,
    const float* __restrict__ w, const int* __restrict__ base,
    int2* __restrict__ sw, int E, int NB, int epc)
{
    __shared__ int cur[MAXNB];
    int c = blockIdx.x;
    for (int b = threadIdx.x; b < NB; b += 512)
        cur[b] = base[b * C_CHUNKS + c];
    __syncthreads();
    int e0 = c * epc, e1 = min(e0 + epc, E);
    for (int e = e0 + (int)threadIdx.x; e < e1; e += 512) {
        int d = dst[e];
        int b = d >> LOG_R;
        int loc = d & (RANGE - 1);
        int pos = atomicAdd(&cur[b], 1);
        sw[pos] = make_int2(src[e] | (loc << 17), __float_as_int(w[e]));
    }
}

// ---------------- conv2: in-LDS node sort + register-accumulate gather -----
// One block per bucket (64 nodes). Stage pairs to LDS, order them by node
// (histogram + scan + index scatter: 2 LDS atomics/edge), then 32 groups of
// 8 threads each own 2 nodes and register-accumulate their contiguous runs
// with a 4-wide unrolled gather. One guarded float4 store per node at end.
__global__ __launch_bounds__(256) void conv2_k(
    const float* __restrict__ h, const int2* __restrict__ sw,
    const int* __restrict__ base, float* __restrict__ out,
    int n, int E, int NB)
{
    __shared__ int2 pairs[CHUNK_P];            // 16 KB
    __shared__ unsigned short order[CHUNK_P];  // 4 KB
    __shared__ int cnt[RANGE];
    __shared__ int sc[RANGE];
    __shared__ int start[RANGE + 1];
    __shared__ int cur[RANGE];

    const int b   = blockIdx.x;
    const int tid = threadIdx.x;
    const int g   = tid >> 3;          // 0..31
    const int cg  = (tid & 7) * 4;

    const int seg0 = base[b * C_CHUNKS];
    const int seg1 = (b + 1 < NB) ? base[(b + 1) * C_CHUNKS] : E;

    float4 accA = make_float4(0.f, 0.f, 0.f, 0.f);  // node 2g
    float4 accB = make_float4(0.f, 0.f, 0.f, 0.f);  // node 2g+1

    for (int cbase = seg0; cbase < seg1; cbase += CHUNK_P) {
        const int m = min(CHUNK_P, seg1 - cbase);

        if (tid < RANGE) cnt[tid] = 0;
        __syncthreads();   // also protects pairs/order reuse across chunks

        for (int i = tid; i < m; i += 256) {
            int2 p = sw[cbase + i];
            pairs[i] = p;
            atomicAdd(&cnt[p.x >> 17], 1);
        }
        __syncthreads();

        // exclusive scan of 64 counts (Hillis-Steele, width 64)
        int v = 0;
        if (tid < RANGE) { v = cnt[tid]; sc[tid] = v; }
        __syncthreads();
        #pragma unroll
        for (int off = 1; off < RANGE; off <<= 1) {
            int x = (tid < RANGE && tid >= off) ? sc[tid - off] : 0;
            __syncthreads();
            if (tid < RANGE) sc[tid] += x;
            __syncthreads();
        }
        if (tid < RANGE) { start[tid] = sc[tid] - v; cur[tid] = sc[tid] - v; }
        if (tid == RANGE - 1) start[RANGE] = sc[RANGE - 1];
        __syncthreads();

        // scatter indices into per-node order
        for (int i = tid; i < m; i += 256) {
            int loc = pairs[i].x >> 17;
            int pos = atomicAdd(&cur[loc], 1);
            order[pos] = (unsigned short)i;
        }
        __syncthreads();

        // gather: group g handles nodes 2g (even) and 2g+1 (odd);
        // their runs are contiguous: [start[2g], start[2g+2])
        int k  = start[2 * g];
        int ke = start[2 * g + 2];
        for (; k + 3 < ke; k += 4) {
            int i0 = order[k + 0], i1 = order[k + 1];
            int i2 = order[k + 2], i3 = order[k + 3];
            int2 p0 = pairs[i0], p1 = pairs[i1], p2 = pairs[i2], p3 = pairs[i3];
            float4 h0 = *reinterpret_cast<const float4*>(h + (size_t)(p0.x & 0x1FFFF) * N_OUT + cg);
            float4 h1 = *reinterpret_cast<const float4*>(h + (size_t)(p1.x & 0x1FFFF) * N_OUT + cg);
            float4 h2 = *reinterpret_cast<const float4*>(h + (size_t)(p2.x & 0x1FFFF) * N_OUT + cg);
            float4 h3 = *reinterpret_cast<const float4*>(h + (size_t)(p3.x & 0x1FFFF) * N_OUT + cg);
            #define ACC_STEP(p, hv)                                            \
            {                                                                  \
                float wv  = __int_as_float(p.y);                               \
                int   odd = (p.x >> 17) & 1;                                   \
                float wa = odd ? 0.f : wv, wb = odd ? wv : 0.f;                \
                accA.x += hv.x * wa; accA.y += hv.y * wa;                      \
                accA.z += hv.z * wa; accA.w += hv.w * wa;                      \
                accB.x += hv.x * wb; accB.y += hv.y * wb;                      \
                accB.z += hv.z * wb; accB.w += hv.w * wb;                      \
            }
            ACC_STEP(p0, h0) ACC_STEP(p1, h1) ACC_STEP(p2, h2) ACC_STEP(p3, h3)
        }
        for (; k < ke; ++k) {
            int i = order[k];
            int2 p = pairs[i];
            float4 hv = *reinterpret_cast<const float4*>(h + (size_t)(p.x & 0x1FFFF) * N_OUT + cg);
            ACC_STEP(p, hv)
            #undef ACC_STEP
        }
        __syncthreads();
    }

    const int lo = b * RANGE;
    int node0 = lo + 2 * g;
    if (node0 < n)
        *reinterpret_cast<float4*>(out + (size_t)node0 * N_OUT + cg) = accA;
    if (node0 + 1 < n)
        *reinterpret_cast<float4*>(out + (size_t)(node0 + 1) * N_OUT + cg) = accB;
}

// ---------------- Fallback: fused (no workspace) ----------------
__global__ __launch_bounds__(256) void fused_edge(
    const float* __restrict__ feat, const float* __restrict__ W,
    const float* __restrict__ edge_w, const int* __restrict__ src,
    const int* __restrict__ dst, float* __restrict__ out, int E)
{
    __shared__ float Ws[N_IN * N_OUT];
    for (int i = threadIdx.x; i < (N_IN * N_OUT) / 4; i += 256)
        reinterpret_cast<float4*>(Ws)[i] = reinterpret_cast<const float4*>(W)[i];
    __syncthreads();
    int gid = blockIdx.x * 256 + threadIdx.x;
    int e = gid >> 3;
    if (e >= E) return;
    int cg = (gid & 7) * 4;
    int s = src[e];
    int d = dst[e];
    float w = edge_w[e];
    const float4* frow = reinterpret_cast<const float4*>(feat + (size_t)s * N_IN);
    float4 acc = make_float4(0.f, 0.f, 0.f, 0.f);
    #pragma unroll
    for (int k4 = 0; k4 < N_IN / 4; ++k4) {
        float4 f = frow[k4];
        int k = k4 * 4;
        float4 w0 = *reinterpret_cast<const float4*>(&Ws[(k + 0) * N_OUT + cg]);
        float4 w1 = *reinterpret_cast<const float4*>(&Ws[(k + 1) * N_OUT + cg]);
        float4 w2 = *reinterpret_cast<const float4*>(&Ws[(k + 2) * N_OUT + cg]);
        float4 w3 = *reinterpret_cast<const float4*>(&Ws[(k + 3) * N_OUT + cg]);
        acc.x += f.x * w0.x + f.y * w1.x + f.z * w2.x + f.w * w3.x;
        acc.y += f.x * w0.y + f.y * w1.y + f.z * w2.y + f.w * w3.y;
        acc.z += f.x * w0.z + f.y * w1.z + f.z * w2.z + f.w * w3.z;
        acc.w += f.x * w0.w + f.y * w1.w + f.z * w2.w + f.w * w3.w;
    }
    float* o = out + (size_t)d * N_OUT + cg;
    atomicAdd(o + 0, acc.x * w);
    atomicAdd(o + 1, acc.y * w);
    atomicAdd(o + 2, acc.z * w);
    atomicAdd(o + 3, acc.w * w);
}

extern "C" void kernel_launch(void* const* d_in, const int* in_sizes, int n_in,
                              void* d_out, int out_size, void* d_ws, size_t ws_size,
                              hipStream_t stream) {
    const float* feat   = (const float*)d_in[0];
    const float* W      = (const float*)d_in[1];
    const float* edge_w = (const float*)d_in[2];
    const int*   src    = (const int*)d_in[3];
    const int*   dst    = (const int*)d_in[4];
    float* out = (float*)d_out;

    int n = in_sizes[0] / N_IN;   // 100000
    int E = in_sizes[2];          // 1600000

    int NB  = (n + RANGE - 1) / RANGE;       // 1563
    int m   = NB * C_CHUNKS;                 // 200,064
    int nsb = (m + SCAN_B - 1) / SCAN_B;     // 391
    int epc = (E + C_CHUNKS - 1) / C_CHUNKS; // 12500

    size_t off_h    = 0;
    size_t off_base = off_h + (size_t)n * N_OUT * sizeof(float);
    size_t off_bsum = off_base + (size_t)m * sizeof(int);
    size_t off_sw   = (off_bsum + (size_t)nsb * sizeof(int) + 15) & ~(size_t)15;
    size_t need     = off_sw + (size_t)E * sizeof(int2);

    char* ws = (char*)d_ws;

    bool ok = (ws_size >= need) && (n <= (1 << 17)) && (NB <= MAXNB);

    if (ok) {
        float* h    = (float*)(ws + off_h);
        int*   base = (int*)(ws + off_base);   // cnt matrix, scanned in place
        int*   bsum = (int*)(ws + off_bsum);
        int2*  sw   = (int2*)(ws + off_sw);

        long gthreads = (long)n * 8;
        gemm_h<<<(int)((gthreads + 255) / 256), 256, 0, stream>>>(feat, W, h, n);

        count_k<<<C_CHUNKS, 512, 0, stream>>>(dst, base, E, NB, epc);
        scan1<<<nsb, SCAN_B, 0, stream>>>(base, bsum, m);
        scan2<<<1, SCAN_B, 0, stream>>>(bsum, nsb);
        scan3<<<nsb, SCAN_B, 0, stream>>>(base, bsum, m);
        partition_k<<<C_CHUNKS, 512, 0, stream>>>(src, dst, edge_w, base, sw, E, NB, epc);
        conv2_k<<<NB, 256, 0, stream>>>(h, sw, base, out, n, E, NB);
    } else {
        hipMemsetAsync(d_out, 0, (size_t)out_size * sizeof(float), stream);
        long sthreads = (long)E * 8;
        fused_edge<<<(int)((sthreads + 255) / 256), 256, 0, stream>>>(feat, W, edge_w, src, dst, out, E);
    }
}